// Round 11
// baseline (320.754 us; speedup 1.0000x reference)
//
#include <hip/hip_runtime.h>
#include <hip/hip_bf16.h>
#include <cstdint>
#include <cstddef>

typedef __bf16 bf16;
typedef __bf16 bf16x8 __attribute__((ext_vector_type(8)));
typedef float f32x4 __attribute__((ext_vector_type(4)));
typedef short short4v __attribute__((ext_vector_type(4)));
typedef unsigned uint2v __attribute__((ext_vector_type(2)));
typedef unsigned uint4v __attribute__((ext_vector_type(4)));

#define GLB_AS(p) ((const __attribute__((address_space(1))) unsigned*)(unsigned long long)(p))
#define LDS_AS(p) ((__attribute__((address_space(3))) unsigned*)(unsigned)(unsigned long long)(p))

__device__ __forceinline__ void g2l16(const void* g, void* l) {
  __builtin_amdgcn_global_load_lds(GLB_AS(g), LDS_AS(l), 16, 0, 0);
}

__device__ __forceinline__ short f2bf(float x) {
  bf16 h = (bf16)x;
  return __builtin_bit_cast(short, h);
}

// packed f32x2 -> bf16x2 convert; memcpy because __hip_bfloat162 is not
// trivially copyable (r14 compile lesson).
__device__ __forceinline__ unsigned pk_bf16(float a, float b) {
  __hip_bfloat162 h = __float22bfloat162_rn(float2{a, b});
  unsigned u;
  __builtin_memcpy(&u, &h, 4);
  return u;
}

// native transcendentals via compiler-visible OCML intrinsics.
// r10 lesson: raw inline-asm v_exp_f32 bypasses the TRANS-use hazard
// recognizer -> NaN. These lower to llvm.amdgcn.{exp2,rcp} with hazards ok.
extern "C" __device__ __attribute__((const)) float __ocml_native_exp2_f32(float);
extern "C" __device__ __attribute__((const)) float __ocml_native_recip_f32(float);
__device__ __forceinline__ float fast_exp2(float x) {
  return __ocml_native_exp2_f32(x);
}
// tanh(a) = 1 - 2/(e^{2a}+1); e^{2a} = 2^{2a*log2(e)}. ~8 VALU vs libm ~40.
__device__ __forceinline__ float fast_tanh(float a) {
  float e = __ocml_native_exp2_f32(a * 2.8853900817779268f);
  return 1.f - 2.f * __ocml_native_recip_f32(e + 1.f);
}

constexpr int MROWS = 4096;            // M (= B*L) for every GEMM in this block
constexpr size_t ATILE = (size_t)MROWS * 32;  // elems per k-tile of an A operand

// q pre-scale: (1/sqrt(64)) * log2(e) -> softmax runs in exp2 domain
#define QSCALE 0.18033688011112042f

// ---------------- shared bodies ----------------
__device__ __forceinline__ void transpose_body(
    const float* __restrict__ in, bf16* __restrict__ out, int K, int N,
    int bx, int by, float (*tile)[33], int tid)
{
  int tx = tid & 31, ty = tid >> 5;           // 32 x 8
  int n0 = bx * 32, k0 = by * 32;
  for (int i = ty; i < 32; i += 8)
    tile[i][tx] = in[(size_t)(k0 + i) * N + n0 + tx];
  __syncthreads();
  bf16* obase = out + (size_t)(k0 >> 5) * N * 32;
  for (int i = ty; i < 32; i += 8)
    obase[(size_t)(n0 + i) * 32 + tx] = (bf16)tile[tx][i];
}

__device__ __forceinline__ void ln_body(
    const float* __restrict__ x, const float* __restrict__ sc,
    const float* __restrict__ bi, bf16* __restrict__ out,
    int row, float* wsum, float* wsq, int tid)
{
  const float* xr = x + (size_t)row * 1024;
  int c = tid * 4;
  float4 xv = *(const float4*)(xr + c);
  float s = xv.x + xv.y + xv.z + xv.w;
  float q = xv.x * xv.x + xv.y * xv.y + xv.z * xv.z + xv.w * xv.w;
#pragma unroll
  for (int off = 1; off < 64; off <<= 1) {
    s += __shfl_xor(s, off);
    q += __shfl_xor(q, off);
  }
  int wv = tid >> 6;
  if ((tid & 63) == 0) { wsum[wv] = s; wsq[wv] = q; }
  __syncthreads();
  s = wsum[0] + wsum[1] + wsum[2] + wsum[3];
  q = wsq[0] + wsq[1] + wsq[2] + wsq[3];
  float mean = s * (1.f / 1024.f);
  float var = q * (1.f / 1024.f) - mean * mean;
  float rstd = rsqrtf(var + 1e-6f);
  float4 scv = *(const float4*)(sc + c);
  float4 biv = *(const float4*)(bi + c);
  bf16* o = out + (size_t)(c >> 5) * ATILE + (size_t)row * 32 + (c & 31);
  o[0] = (bf16)((xv.x - mean) * rstd * scv.x + biv.x);
  o[1] = (bf16)((xv.y - mean) * rstd * scv.y + biv.y);
  o[2] = (bf16)((xv.z - mean) * rstd * scv.z + biv.z);
  o[3] = (bf16)((xv.w - mean) * rstd * scv.w + biv.w);
}

// ---------------- fused prologue: 4 weight transposes + ln1 ----------------
__global__ __launch_bounds__(256) void prep_kernel(
    const float* __restrict__ wqkv, const float* __restrict__ wproj,
    const float* __restrict__ wmlp1, const float* __restrict__ wmlp2,
    bf16* __restrict__ wqkv_t, bf16* __restrict__ wproj_t,
    bf16* __restrict__ wmlp1_t, bf16* __restrict__ wmlp2_t,
    const float* __restrict__ x, const float* __restrict__ ln1s,
    const float* __restrict__ ln1b, bf16* __restrict__ hbuf)
{
  __shared__ float tile[32][33];
  __shared__ float wsum[4], wsq[4];
  int bid = blockIdx.x, tid = threadIdx.x;
  if (bid < 3072)
    transpose_body(wqkv, wqkv_t, 1024, 3072, bid % 96, bid / 96, tile, tid);
  else if (bid < 4096) {
    int i = bid - 3072;
    transpose_body(wproj, wproj_t, 1024, 1024, i % 32, i / 32, tile, tid);
  } else if (bid < 8192) {
    int i = bid - 4096;
    transpose_body(wmlp1, wmlp1_t, 1024, 4096, i % 128, i / 128, tile, tid);
  } else if (bid < 12288) {
    int i = bid - 8192;
    transpose_body(wmlp2, wmlp2_t, 4096, 1024, i % 32, i / 32, tile, tid);
  } else {
    ln_body(x, ln1s, ln1b, hbuf, bid - 12288, wsum, wsq, tid);
  }
}

// ---------------- standalone layernorm (ln2) ----------------
__global__ __launch_bounds__(256) void ln_kernel(
    const float* __restrict__ x, const float* __restrict__ sc,
    const float* __restrict__ bi, bf16* __restrict__ out)
{
  __shared__ float wsum[4], wsq[4];
  ln_body(x, sc, bi, out, blockIdx.x, wsum, wsq, threadIdx.x);
}

// ---------------- GEMM on K-tiled operands (2-phase double buffer) -------
// A: bf16 [K/32][4096][32], B: bf16 [K/32][N][32].  C[M,N] = A @ B^T.
// KS = k-tiles staged per phase (BK = 32*KS); KS=2 for the small-N
// latency-bound instances (proj/mlp2).
// EPI 0: qkv scatter; EPI 1: outf = v + bias + resid (fp32).
template <int MT, int NT, int KS, int EPI>
__global__ __launch_bounds__(256) void gemm_tt(
    const bf16* __restrict__ A, const bf16* __restrict__ Bt,
    int N, int K,
    const float* __restrict__ bias, const float* __restrict__ resid,
    float* __restrict__ outf, bf16* __restrict__ ob0,
    bf16* __restrict__ ob1, bf16* __restrict__ ob2)
{
  constexpr int TM = MT * 32, TN = NT * 32;
  __shared__ __align__(16) bf16 As[2][TM * 32 * KS];
  __shared__ __align__(16) bf16 Bs[2][TN * 32 * KS];
  const int tid = threadIdx.x, lane = tid & 63, wave = tid >> 6;
  const int wm = wave >> 1, wn = wave & 1;
  const int quad = lane >> 4, l16 = lane & 15;

  int flat = blockIdx.x + gridDim.x * blockIdx.y;
  int xcd = flat & 7, rr = flat >> 3;
  int npx = gridDim.x >> 3;
  int bn = xcd * npx + (rr % npx);
  int bm = rr / npx;

  const size_t astride = ATILE;
  const size_t bstride = (size_t)N * 32;
  const bf16* Abase = A + (size_t)bm * TM * 32 + (size_t)lane * 8;
  const bf16* Bbase = Bt + (size_t)bn * TN * 32 + (size_t)lane * 8;

  f32x4 acc[MT][NT] = {};
  const int KT = K / (32 * KS);

  auto stage = [&](int buf, int kt) {
#pragma unroll
    for (int ks = 0; ks < KS; ks++) {
      const bf16* Ab = Abase + (size_t)(kt * KS + ks) * astride;
      const bf16* Bb = Bbase + (size_t)(kt * KS + ks) * bstride;
#pragma unroll
      for (int i = 0; i < MT / 2; i++)
        g2l16(Ab + (wave + 4 * i) * 512, &As[buf][ks * TM * 32 + (wave + 4 * i) * 512]);
#pragma unroll
      for (int i = 0; i < NT / 2; i++)
        g2l16(Bb + (wave + 4 * i) * 512, &Bs[buf][ks * TN * 32 + (wave + 4 * i) * 512]);
    }
  };

  stage(0, 0);
  int buf = 0;
  for (int kt = 0; kt < KT; kt++) {
    __syncthreads();
    if (kt + 1 < KT) stage(buf ^ 1, kt + 1);
#pragma unroll
    for (int kk = 0; kk < KS; kk++) {
      bf16x8 af[MT], bfr[NT];
#pragma unroll
      for (int mt = 0; mt < MT; mt++)
        af[mt] = *(const bf16x8*)&As[buf][kk * TM * 32 + (wm * MT * 16 + mt * 16 + l16) * 32 + quad * 8];
#pragma unroll
      for (int nt = 0; nt < NT; nt++)
        bfr[nt] = *(const bf16x8*)&Bs[buf][kk * TN * 32 + (wn * NT * 16 + nt * 16 + l16) * 32 + quad * 8];
#pragma unroll
      for (int mt = 0; mt < MT; mt++)
#pragma unroll
        for (int nt = 0; nt < NT; nt++)
          acc[mt][nt] = __builtin_amdgcn_mfma_f32_16x16x32_bf16(af[mt], bfr[nt], acc[mt][nt], 0, 0, 0);
    }
    buf ^= 1;
  }

#pragma unroll
  for (int mt = 0; mt < MT; mt++) {
#pragma unroll
    for (int nt = 0; nt < NT; nt++) {
      int row0 = bm * TM + wm * MT * 16 + mt * 16 + quad * 4;
      int col = bn * TN + wn * NT * 16 + nt * 16 + l16;
      if (EPI == 0) {
        int b = row0 >> 11, l = row0 & 2047;
        int which = col >> 10, d = col & 1023;
        int hh = d >> 6, hdi = d & 63;
        size_t bh = (size_t)(b * 16 + hh);
        if (which == 0) {
#pragma unroll
          for (int r = 0; r < 4; r++)
            ob0[(bh * 2048 + l + r) * 64 + hdi] = (bf16)(acc[mt][nt][r] * QSCALE);
        } else if (which == 1) {
#pragma unroll
          for (int r = 0; r < 4; r++)
            ob1[(bh * 2048 + l + r) * 64 + hdi] = (bf16)acc[mt][nt][r];
        } else {
          short4v v4;
#pragma unroll
          for (int r = 0; r < 4; r++) v4[r] = f2bf(acc[mt][nt][r]);
          *(short4v*)&ob2[(bh * 64 + hdi) * 2048 + l] = v4;
        }
      } else {
#pragma unroll
        for (int r = 0; r < 4; r++) {
          int row = row0 + r;
          float v = acc[mt][nt][r];
          size_t idx = (size_t)row * N + col;
          outf[idx] = v + bias[col] + resid[idx];
        }
      }
    }
  }
}

// ---------------- 8-phase 256x256 GEMM (mlp1: M=N=4096, K=1024) ------
// m201-template port; see R7 notes. Verified win (mlp1 off top-5).
// qkv stays on the 2-phase 128x128 path: the 8-phase 192-block variant
// measured neutral-to-negative (R10: 25% CU idle cancels the schedule).
__global__ __launch_bounds__(512, 2) void gemm8p_gelu(
    const bf16* __restrict__ A, const bf16* __restrict__ Bt,
    const float* __restrict__ bias, bf16* __restrict__ ob0)
{
  __shared__ __align__(16) bf16 As[4 * 8192];   // [buf][kk][256][32] 64KB
  __shared__ __align__(16) bf16 Bs[4 * 8192];   // [buf][kk][256][32] 64KB
  const int tid = threadIdx.x, lane = tid & 63, wave = tid >> 6;
  const int quad = lane >> 4, l16 = lane & 15;
  const int wm = wave >> 2, wn = wave & 3;       // 2 x 4 wave grid

  int flat = blockIdx.x + gridDim.x * blockIdx.y; // grid 16x16 = 256
  int xcd = flat & 7, rr = flat >> 3;
  int bn = xcd * 2 + (rr & 1);
  int bm = rr >> 1;

  auto stA = [&](int buf, int ktile, int half) {
    const bf16* g = A + (size_t)ktile * ATILE +
                    ((size_t)bm * 256 + half * 128) * 32 + (size_t)tid * 8;
    g2l16(g, &As[(buf * 2 + (ktile & 1)) * 8192 + half * 4096 + wave * 512]);
  };
  auto stB = [&](int buf, int ktile, int half) {
    const bf16* g = Bt + (size_t)ktile * ATILE +
                    ((size_t)bn * 256 + half * 128) * 32 + (size_t)tid * 8;
    g2l16(g, &Bs[(buf * 2 + (ktile & 1)) * 8192 + half * 4096 + wave * 512]);
  };

  f32x4 acc[8][4] = {};
  bf16x8 af[4][2], bfr[4][2];

  stA(0, 0, 0); stA(0, 0, 1); stA(0, 1, 0); stA(0, 1, 1);
  stB(0, 0, 0); stB(0, 0, 1); stB(0, 1, 0); stB(0, 1, 1);
  asm volatile("s_waitcnt vmcnt(0)" ::: "memory");
  __builtin_amdgcn_s_barrier();

  for (int kt = 0; kt < 16; kt++) {
    const int buf = kt & 1, nbuf = buf ^ 1;
    const bool more = (kt + 1) < 16;
    const int kA = (kt + 1) * 2;

    // ---- phase 1
#pragma unroll
    for (int mt = 0; mt < 4; mt++)
#pragma unroll
      for (int kk = 0; kk < 2; kk++)
        af[mt][kk] = *(const bf16x8*)&As[(buf * 2 + kk) * 8192 +
                       (wm * 128 + mt * 16 + l16) * 32 + quad * 8];
#pragma unroll
    for (int nt = 0; nt < 2; nt++)
#pragma unroll
      for (int kk = 0; kk < 2; kk++)
        bfr[nt][kk] = *(const bf16x8*)&Bs[(buf * 2 + kk) * 8192 +
                        (wn * 64 + nt * 16 + l16) * 32 + quad * 8];
    if (more) { stA(nbuf, kA, 0); stA(nbuf, kA, 1); stA(nbuf, kA + 1, 0); stA(nbuf, kA + 1, 1); }
    __builtin_amdgcn_s_barrier();
    asm volatile("s_waitcnt lgkmcnt(0)" ::: "memory");
    __builtin_amdgcn_sched_barrier(0);
    __builtin_amdgcn_s_setprio(1);
#pragma unroll
    for (int mt = 0; mt < 4; mt++)
#pragma unroll
      for (int nt = 0; nt < 2; nt++)
#pragma unroll
        for (int kk = 0; kk < 2; kk++)
          acc[mt][nt] = __builtin_amdgcn_mfma_f32_16x16x32_bf16(af[mt][kk], bfr[nt][kk], acc[mt][nt], 0, 0, 0);
    __builtin_amdgcn_s_setprio(0);
    __builtin_amdgcn_s_barrier();

    // ---- phase 2
#pragma unroll
    for (int nt = 2; nt < 4; nt++)
#pragma unroll
      for (int kk = 0; kk < 2; kk++)
        bfr[nt][kk] = *(const bf16x8*)&Bs[(buf * 2 + kk) * 8192 +
                        (wn * 64 + nt * 16 + l16) * 32 + quad * 8];
    if (more) { stB(nbuf, kA, 0); stB(nbuf, kA, 1); stB(nbuf, kA + 1, 0); stB(nbuf, kA + 1, 1); }
    __builtin_amdgcn_s_barrier();
    asm volatile("s_waitcnt lgkmcnt(0)" ::: "memory");
    __builtin_amdgcn_sched_barrier(0);
    __builtin_amdgcn_s_setprio(1);
#pragma unroll
    for (int mt = 0; mt < 4; mt++)
#pragma unroll
      for (int nt = 2; nt < 4; nt++)
#pragma unroll
        for (int kk = 0; kk < 2; kk++)
          acc[mt][nt] = __builtin_amdgcn_mfma_f32_16x16x32_bf16(af[mt][kk], bfr[nt][kk], acc[mt][nt], 0, 0, 0);
    __builtin_amdgcn_s_setprio(0);
    __builtin_amdgcn_s_barrier();

    // ---- phase 3
#pragma unroll
    for (int mt = 0; mt < 4; mt++)
#pragma unroll
      for (int kk = 0; kk < 2; kk++)
        af[mt][kk] = *(const bf16x8*)&As[(buf * 2 + kk) * 8192 +
                       (wm * 128 + (mt + 4) * 16 + l16) * 32 + quad * 8];
    __builtin_amdgcn_s_barrier();
    asm volatile("s_waitcnt lgkmcnt(0)" ::: "memory");
    __builtin_amdgcn_sched_barrier(0);
    __builtin_amdgcn_s_setprio(1);
#pragma unroll
    for (int mt = 0; mt < 4; mt++)
#pragma unroll
      for (int nt = 0; nt < 2; nt++)
#pragma unroll
        for (int kk = 0; kk < 2; kk++)
          acc[mt + 4][nt] = __builtin_amdgcn_mfma_f32_16x16x32_bf16(af[mt][kk], bfr[nt][kk], acc[mt + 4][nt], 0, 0, 0);
    __builtin_amdgcn_s_setprio(0);
    __builtin_amdgcn_s_barrier();

    // ---- phase 4
    __builtin_amdgcn_s_setprio(1);
#pragma unroll
    for (int mt = 0; mt < 4; mt++)
#pragma unroll
      for (int nt = 2; nt < 4; nt++)
#pragma unroll
        for (int kk = 0; kk < 2; kk++)
          acc[mt + 4][nt] = __builtin_amdgcn_mfma_f32_16x16x32_bf16(af[mt][kk], bfr[nt][kk], acc[mt + 4][nt], 0, 0, 0);
    __builtin_amdgcn_s_setprio(0);
    asm volatile("s_waitcnt vmcnt(0)" ::: "memory");
    __builtin_amdgcn_s_barrier();
  }

#pragma unroll
  for (int mt = 0; mt < 8; mt++) {
#pragma unroll
    for (int nt = 0; nt < 4; nt++) {
      int row0 = bm * 256 + wm * 128 + mt * 16 + quad * 4;
      int col = bn * 256 + wn * 64 + nt * 16 + l16;
      float bcol = bias[col];
#pragma unroll
      for (int r = 0; r < 4; r++) {
        int row = row0 + r;
        float t = acc[mt][nt][r] + bcol;
        float a = 0.7978845608028654f * t * (1.f + 0.044715f * t * t);
        float g = 0.5f * t * (1.f + fast_tanh(a));
        ob0[(size_t)(col >> 5) * ATILE + (size_t)row * 32 + (col & 31)] = (bf16)g;
      }
    }
  }
}

// ---------------- flash attention v15 ----------------
// v14 + double-buffered LDS, ONE barrier per kt. R10 accounting: 7.6k
// cyc/kt elapsed vs ~1.5k MFMA + 0.7k VALU need -> ~5k stall from the
// 2-barrier lockstep (all waves write LDS, barrier, all compute, barrier).
// v15: Ks/Vs x2 (64KB, still 2 blocks/CU = grid max). Loads for kt+1
// issue at top of kt (full-iteration latency cover, as before); writes go
// to buf^1 AFTER compute (no conflict with reads of buf); one
// __syncthreads() publishes. WAR: reads of buf^1 (kt-1) end before
// barrier(kt) < writes (kt); RAW: writes (kt) end before barrier(kt+1)
// < reads (kt+1). Compute/softmax/full-rate-PV unchanged from v14.
__global__ __launch_bounds__(256, 2) void flash_attn(
    const bf16* __restrict__ Q, const bf16* __restrict__ Kg,
    const bf16* __restrict__ Vg, bf16* __restrict__ O)
{
  __shared__ __align__(16) bf16 Ks[2][128 * 64];  // [buf][virt kpos][hd]
  __shared__ __align__(16) bf16 Vs[2][64 * 128];  // [buf][hd][kpos]
  const int tid = threadIdx.x, lane = tid & 63, wave = tid >> 6;
  const int quad = lane >> 4, l16 = lane & 15;
  const int qt = blockIdx.x, bh = blockIdx.y;
  const int b = bh >> 4, h = bh & 15;

  const bf16* qg = Q + ((size_t)bh * 2048 + qt * 128) * 64;
  const bf16* kg = Kg + (size_t)bh * 2048 * 64;
  const bf16* vg = Vg + (size_t)bh * 64 * 2048;

  // K write: actual row a0 = tid>>3 -> virtual row v0 (kpos permutation for
  // full-rate PV); pass i advances +32 rows = +4096B (swizzle invariant).
  const int a0 = tid >> 3;
  const int a5 = a0 & 31;
  const int vb = ((a5 >> 2) & 1) * 16 + (a5 >> 3) * 4 + (a5 & 3);
  const int v0 = (a0 & ~31) + vb;
  const int kw0 = (v0 << 7) + (((tid & 7) << 4) ^ ((v0 & 7) << 4));
  const int vw0 = ((tid >> 4) << 8) + (((tid & 15) << 4) ^ (((tid >> 4) & 7) << 4));

  bf16x8 qf[2][2];
#pragma unroll
  for (int s = 0; s < 2; s++)
#pragma unroll
    for (int kk = 0; kk < 2; kk++)
      qf[s][kk] = *(const bf16x8*)&qg[(size_t)(wave * 32 + s * 16 + l16) * 64 + kk * 32 + quad * 8];

  f32x4 oacc[2][4] = {};
  float lrow[2] = {0.f, 0.f};   // lane-local partials; reduced once at end

  // prologue: load tile 0 and write into buf 0
  bf16x8 kreg[4], vreg[4];
#pragma unroll
  for (int i = 0; i < 4; i++) {
    int t = tid + i * 256;
    kreg[i] = *(const bf16x8*)&kg[(size_t)(t >> 3) * 64 + (t & 7) * 8];
    vreg[i] = *(const bf16x8*)&vg[(size_t)(t >> 4) * 2048 + (t & 15) * 8];
  }
#pragma unroll
  for (int i = 0; i < 4; i++) {
    *(bf16x8*)((char*)&Ks[0][0] + kw0 + i * 4096) = kreg[i];
    *(bf16x8*)((char*)&Vs[0][0] + vw0 + i * 4096) = vreg[i];
  }

  for (int kt = 0; kt < 16; kt++) {
    const int buf = kt & 1;
    if (kt < 15) {                      // issue loads for kt+1 early
#pragma unroll
      for (int i = 0; i < 4; i++) {
        int t = tid + i * 256;
        kreg[i] = *(const bf16x8*)&kg[((size_t)(kt + 1) * 128 + (t >> 3)) * 64 + (t & 7) * 8];
        vreg[i] = *(const bf16x8*)&vg[(size_t)(t >> 4) * 2048 + (kt + 1) * 128 + (t & 15) * 8];
      }
    }
    __syncthreads();                    // publish buf; fence buf^1 reads

    // S^T = K.Q^T : 8 virtual kpos-tiles x 2 q-subtiles, K-dim 64 = 2 chunks
    f32x4 sacc[2][8] = {};
#pragma unroll
    for (int kk = 0; kk < 2; kk++) {
#pragma unroll
      for (int ct = 0; ct < 8; ct++) {
        int krow = ct * 16 + l16;
        bf16x8 kf = *(const bf16x8*)((const char*)&Ks[buf][0] + krow * 128 +
                                     ((kk * 64 + quad * 16) ^ ((l16 & 7) << 4)));
        sacc[0][ct] = __builtin_amdgcn_mfma_f32_16x16x32_bf16(kf, qf[0][kk], sacc[0][ct], 0, 0, 0);
        sacc[1][ct] = __builtin_amdgcn_mfma_f32_16x16x32_bf16(kf, qf[1][kk], sacc[1][ct], 0, 0, 0);
      }
    }

    // no-max softmax (exp2 domain); pack ct-pairs into K=32 B-fragments
    bf16x8 pf[2][4];
#pragma unroll
    for (int s = 0; s < 2; s++) {
      float sum = 0.f;
#pragma unroll
      for (int c = 0; c < 4; c++) {
        uint4v u;
#pragma unroll
        for (int bb = 0; bb < 2; bb++) {
          float p0 = fast_exp2(sacc[s][2 * c + bb][0]);
          float p1 = fast_exp2(sacc[s][2 * c + bb][1]);
          float p2 = fast_exp2(sacc[s][2 * c + bb][2]);
          float p3 = fast_exp2(sacc[s][2 * c + bb][3]);
          sum += (p0 + p1) + (p2 + p3);
          u[bb * 2 + 0] = pk_bf16(p0, p1);
          u[bb * 2 + 1] = pk_bf16(p2, p3);
        }
        pf[s][c] = __builtin_bit_cast(bf16x8, u);
      }
      lrow[s] += sum;
    }

    // O^T += V^T . P^T at full K=32 rate
#pragma unroll
    for (int ot = 0; ot < 4; ot++) {
#pragma unroll
      for (int c = 0; c < 4; c++) {
        int vrow = ot * 16 + l16;
        bf16x8 vf = *(const bf16x8*)((const char*)&Vs[buf][0] + vrow * 256 +
                                     ((c * 64 + quad * 16) ^ ((l16 & 7) << 4)));
        oacc[0][ot] = __builtin_amdgcn_mfma_f32_16x16x32_bf16(vf, pf[0][c], oacc[0][ot], 0, 0, 0);
        oacc[1][ot] = __builtin_amdgcn_mfma_f32_16x16x32_bf16(vf, pf[1][c], oacc[1][ot], 0, 0, 0);
      }
    }

    if (kt < 15) {                      // write kt+1 into the other buffer
#pragma unroll
      for (int i = 0; i < 4; i++) {
        *(bf16x8*)((char*)&Ks[buf ^ 1][0] + kw0 + i * 4096) = kreg[i];
        *(bf16x8*)((char*)&Vs[buf ^ 1][0] + vw0 + i * 4096) = vreg[i];
      }
    }
  }

  // epilogue: finish lrow reduce (quads hold disjoint kpos partials), store
#pragma unroll
  for (int s = 0; s < 2; s++) {
    float l = lrow[s];
    l += __shfl_xor(l, 16);
    l += __shfl_xor(l, 32);
    float inv = 1.f / l;
    int qrow = qt * 128 + wave * 32 + s * 16 + l16;
    size_t grow = (size_t)b * 2048 + qrow;
#pragma unroll
    for (int ot = 0; ot < 4; ot++) {
      int col = h * 64 + ot * 16 + quad * 4;
      short4v o4;
#pragma unroll
      for (int r = 0; r < 4; r++) o4[r] = f2bf(oacc[s][ot][r] * inv);
      *(short4v*)&O[(size_t)(col >> 5) * ATILE + grow * 32 + (col & 31)] = o4;
    }
  }
}

// ---------------- launch ----------------
extern "C" void kernel_launch(void* const* d_in, const int* in_sizes, int n_in,
                              void* d_out, int out_size, void* d_ws, size_t ws_size,
                              hipStream_t stream)
{
  const float* x     = (const float*)d_in[0];
  const float* ln1s  = (const float*)d_in[1];
  const float* ln1b  = (const float*)d_in[2];
  const float* wqkv  = (const float*)d_in[3];
  const float* wproj = (const float*)d_in[4];
  const float* bproj = (const float*)d_in[5];
  const float* ln2s  = (const float*)d_in[6];
  const float* ln2b  = (const float*)d_in[7];
  const float* wmlp1 = (const float*)d_in[8];
  const float* bmlp1 = (const float*)d_in[9];
  const float* wmlp2 = (const float*)d_in[10];
  const float* bmlp2 = (const float*)d_in[11];
  float* out = (float*)d_out;

  char* ws = (char*)d_ws;
  bf16* wqkv_t  = (bf16*)(ws + 0);          // tiled [32][3072][32]
  bf16* wproj_t = (bf16*)(ws + 6291456);    // tiled [32][1024][32]
  bf16* wmlp1_t = (bf16*)(ws + 8388608);    // tiled [32][4096][32]
  bf16* wmlp2_t = (bf16*)(ws + 16777216);   // tiled [128][1024][32]
  bf16* hbuf    = (bf16*)(ws + 25165824);   // tiled [32][4096][32]
  bf16* qb      = (bf16*)(ws + 33554432);   // [32,2048,64]
  bf16* kb      = (bf16*)(ws + 41943040);   // [32,2048,64]
  bf16* vb      = (bf16*)(ws + 50331648);   // [32,64,2048]
  bf16* aout    = (bf16*)(ws + 58720256);   // tiled [32][4096][32]
  bf16* mbuf    = (bf16*)(ws + 33554432);   // tiled [128][4096][32] aliases q/k/v/aout

  prep_kernel<<<16384, 256, 0, stream>>>(wqkv, wproj, wmlp1, wmlp2,
                                         wqkv_t, wproj_t, wmlp1_t, wmlp2_t,
                                         x, ln1s, ln1b, hbuf);
  // qkv: 2-phase 128x128 (measured best for this shape, R9/R10 A/B)
  gemm_tt<4, 4, 1, 0><<<dim3(24, 32), 256, 0, stream>>>(hbuf, wqkv_t, 3072, 1024,
                                                        nullptr, nullptr, nullptr, qb, kb, vb);
  flash_attn<<<dim3(16, 32), 256, 0, stream>>>(qb, kb, vb, aout);
  gemm_tt<2, 4, 2, 1><<<dim3(8, 64), 256, 0, stream>>>(aout, wproj_t, 1024, 1024,
                                                       bproj, x, out, nullptr, nullptr, nullptr);
  ln_kernel<<<4096, 256, 0, stream>>>(out, ln2s, ln2b, hbuf);
  // mlp1: 8-phase 256x256 kernel, grid 16x16 = 256 blocks = 1/CU
  gemm8p_gelu<<<dim3(16, 16), 512, 0, stream>>>(hbuf, wmlp1_t, bmlp1, mbuf);
  gemm_tt<2, 4, 2, 1><<<dim3(8, 64), 256, 0, stream>>>(mbuf, wmlp2_t, 1024, 4096,
                                                       bmlp2, out, out, nullptr, nullptr, nullptr);
}

// Round 12
// 308.712 us; speedup vs baseline: 1.0390x; 1.0390x over previous
//
#include <hip/hip_runtime.h>
#include <hip/hip_bf16.h>
#include <cstdint>
#include <cstddef>

typedef __bf16 bf16;
typedef __bf16 bf16x8 __attribute__((ext_vector_type(8)));
typedef float f32x4 __attribute__((ext_vector_type(4)));
typedef short short4v __attribute__((ext_vector_type(4)));
typedef unsigned uint2v __attribute__((ext_vector_type(2)));
typedef unsigned uint4v __attribute__((ext_vector_type(4)));

#define GLB_AS(p) ((const __attribute__((address_space(1))) unsigned*)(unsigned long long)(p))
#define LDS_AS(p) ((__attribute__((address_space(3))) unsigned*)(unsigned)(unsigned long long)(p))

__device__ __forceinline__ void g2l16(const void* g, void* l) {
  __builtin_amdgcn_global_load_lds(GLB_AS(g), LDS_AS(l), 16, 0, 0);
}

__device__ __forceinline__ short f2bf(float x) {
  bf16 h = (bf16)x;
  return __builtin_bit_cast(short, h);
}

// packed f32x2 -> bf16x2 convert; memcpy because __hip_bfloat162 is not
// trivially copyable (r14 compile lesson).
__device__ __forceinline__ unsigned pk_bf16(float a, float b) {
  __hip_bfloat162 h = __float22bfloat162_rn(float2{a, b});
  unsigned u;
  __builtin_memcpy(&u, &h, 4);
  return u;
}

// native transcendentals via compiler-visible OCML intrinsics.
// r10 lesson: raw inline-asm v_exp_f32 bypasses the TRANS-use hazard
// recognizer -> NaN. These lower to llvm.amdgcn.{exp2,rcp} with hazards ok.
extern "C" __device__ __attribute__((const)) float __ocml_native_exp2_f32(float);
extern "C" __device__ __attribute__((const)) float __ocml_native_recip_f32(float);
__device__ __forceinline__ float fast_exp2(float x) {
  return __ocml_native_exp2_f32(x);
}
// tanh(a) = 1 - 2/(e^{2a}+1); e^{2a} = 2^{2a*log2(e)}. ~8 VALU vs libm ~40.
__device__ __forceinline__ float fast_tanh(float a) {
  float e = __ocml_native_exp2_f32(a * 2.8853900817779268f);
  return 1.f - 2.f * __ocml_native_recip_f32(e + 1.f);
}

constexpr int MROWS = 4096;            // M (= B*L) for every GEMM in this block
constexpr size_t ATILE = (size_t)MROWS * 32;  // elems per k-tile of an A operand

// q pre-scale: (1/sqrt(64)) * log2(e) -> softmax runs in exp2 domain
#define QSCALE 0.18033688011112042f

// ---------------- shared bodies ----------------
__device__ __forceinline__ void transpose_body(
    const float* __restrict__ in, bf16* __restrict__ out, int K, int N,
    int bx, int by, float (*tile)[33], int tid)
{
  int tx = tid & 31, ty = tid >> 5;           // 32 x 8
  int n0 = bx * 32, k0 = by * 32;
  for (int i = ty; i < 32; i += 8)
    tile[i][tx] = in[(size_t)(k0 + i) * N + n0 + tx];
  __syncthreads();
  bf16* obase = out + (size_t)(k0 >> 5) * N * 32;
  for (int i = ty; i < 32; i += 8)
    obase[(size_t)(n0 + i) * 32 + tx] = (bf16)tile[tx][i];
}

__device__ __forceinline__ void ln_body(
    const float* __restrict__ x, const float* __restrict__ sc,
    const float* __restrict__ bi, bf16* __restrict__ out,
    int row, float* wsum, float* wsq, int tid)
{
  const float* xr = x + (size_t)row * 1024;
  int c = tid * 4;
  float4 xv = *(const float4*)(xr + c);
  float s = xv.x + xv.y + xv.z + xv.w;
  float q = xv.x * xv.x + xv.y * xv.y + xv.z * xv.z + xv.w * xv.w;
#pragma unroll
  for (int off = 1; off < 64; off <<= 1) {
    s += __shfl_xor(s, off);
    q += __shfl_xor(q, off);
  }
  int wv = tid >> 6;
  if ((tid & 63) == 0) { wsum[wv] = s; wsq[wv] = q; }
  __syncthreads();
  s = wsum[0] + wsum[1] + wsum[2] + wsum[3];
  q = wsq[0] + wsq[1] + wsq[2] + wsq[3];
  float mean = s * (1.f / 1024.f);
  float var = q * (1.f / 1024.f) - mean * mean;
  float rstd = rsqrtf(var + 1e-6f);
  float4 scv = *(const float4*)(sc + c);
  float4 biv = *(const float4*)(bi + c);
  bf16* o = out + (size_t)(c >> 5) * ATILE + (size_t)row * 32 + (c & 31);
  o[0] = (bf16)((xv.x - mean) * rstd * scv.x + biv.x);
  o[1] = (bf16)((xv.y - mean) * rstd * scv.y + biv.y);
  o[2] = (bf16)((xv.z - mean) * rstd * scv.z + biv.z);
  o[3] = (bf16)((xv.w - mean) * rstd * scv.w + biv.w);
}

// ---------------- fused prologue: 4 weight transposes + ln1 ----------------
__global__ __launch_bounds__(256) void prep_kernel(
    const float* __restrict__ wqkv, const float* __restrict__ wproj,
    const float* __restrict__ wmlp1, const float* __restrict__ wmlp2,
    bf16* __restrict__ wqkv_t, bf16* __restrict__ wproj_t,
    bf16* __restrict__ wmlp1_t, bf16* __restrict__ wmlp2_t,
    const float* __restrict__ x, const float* __restrict__ ln1s,
    const float* __restrict__ ln1b, bf16* __restrict__ hbuf)
{
  __shared__ float tile[32][33];
  __shared__ float wsum[4], wsq[4];
  int bid = blockIdx.x, tid = threadIdx.x;
  if (bid < 3072)
    transpose_body(wqkv, wqkv_t, 1024, 3072, bid % 96, bid / 96, tile, tid);
  else if (bid < 4096) {
    int i = bid - 3072;
    transpose_body(wproj, wproj_t, 1024, 1024, i % 32, i / 32, tile, tid);
  } else if (bid < 8192) {
    int i = bid - 4096;
    transpose_body(wmlp1, wmlp1_t, 1024, 4096, i % 128, i / 128, tile, tid);
  } else if (bid < 12288) {
    int i = bid - 8192;
    transpose_body(wmlp2, wmlp2_t, 4096, 1024, i % 32, i / 32, tile, tid);
  } else {
    ln_body(x, ln1s, ln1b, hbuf, bid - 12288, wsum, wsq, tid);
  }
}

// ---------------- standalone layernorm (ln2) ----------------
__global__ __launch_bounds__(256) void ln_kernel(
    const float* __restrict__ x, const float* __restrict__ sc,
    const float* __restrict__ bi, bf16* __restrict__ out)
{
  __shared__ float wsum[4], wsq[4];
  ln_body(x, sc, bi, out, blockIdx.x, wsum, wsq, threadIdx.x);
}

// ---------------- GEMM on K-tiled operands (2-phase double buffer) -------
// A: bf16 [K/32][4096][32], B: bf16 [K/32][N][32].  C[M,N] = A @ B^T.
// KS = k-tiles staged per phase (BK = 32*KS); KS=2 for the small-N
// latency-bound instances (proj/mlp2).
// EPI 0: qkv scatter; EPI 1: outf = v + bias + resid (fp32).
template <int MT, int NT, int KS, int EPI>
__global__ __launch_bounds__(256) void gemm_tt(
    const bf16* __restrict__ A, const bf16* __restrict__ Bt,
    int N, int K,
    const float* __restrict__ bias, const float* __restrict__ resid,
    float* __restrict__ outf, bf16* __restrict__ ob0,
    bf16* __restrict__ ob1, bf16* __restrict__ ob2)
{
  constexpr int TM = MT * 32, TN = NT * 32;
  __shared__ __align__(16) bf16 As[2][TM * 32 * KS];
  __shared__ __align__(16) bf16 Bs[2][TN * 32 * KS];
  const int tid = threadIdx.x, lane = tid & 63, wave = tid >> 6;
  const int wm = wave >> 1, wn = wave & 1;
  const int quad = lane >> 4, l16 = lane & 15;

  int flat = blockIdx.x + gridDim.x * blockIdx.y;
  int xcd = flat & 7, rr = flat >> 3;
  int npx = gridDim.x >> 3;
  int bn = xcd * npx + (rr % npx);
  int bm = rr / npx;

  const size_t astride = ATILE;
  const size_t bstride = (size_t)N * 32;
  const bf16* Abase = A + (size_t)bm * TM * 32 + (size_t)lane * 8;
  const bf16* Bbase = Bt + (size_t)bn * TN * 32 + (size_t)lane * 8;

  f32x4 acc[MT][NT] = {};
  const int KT = K / (32 * KS);

  auto stage = [&](int buf, int kt) {
#pragma unroll
    for (int ks = 0; ks < KS; ks++) {
      const bf16* Ab = Abase + (size_t)(kt * KS + ks) * astride;
      const bf16* Bb = Bbase + (size_t)(kt * KS + ks) * bstride;
#pragma unroll
      for (int i = 0; i < MT / 2; i++)
        g2l16(Ab + (wave + 4 * i) * 512, &As[buf][ks * TM * 32 + (wave + 4 * i) * 512]);
#pragma unroll
      for (int i = 0; i < NT / 2; i++)
        g2l16(Bb + (wave + 4 * i) * 512, &Bs[buf][ks * TN * 32 + (wave + 4 * i) * 512]);
    }
  };

  stage(0, 0);
  int buf = 0;
  for (int kt = 0; kt < KT; kt++) {
    __syncthreads();
    if (kt + 1 < KT) stage(buf ^ 1, kt + 1);
#pragma unroll
    for (int kk = 0; kk < KS; kk++) {
      bf16x8 af[MT], bfr[NT];
#pragma unroll
      for (int mt = 0; mt < MT; mt++)
        af[mt] = *(const bf16x8*)&As[buf][kk * TM * 32 + (wm * MT * 16 + mt * 16 + l16) * 32 + quad * 8];
#pragma unroll
      for (int nt = 0; nt < NT; nt++)
        bfr[nt] = *(const bf16x8*)&Bs[buf][kk * TN * 32 + (wn * NT * 16 + nt * 16 + l16) * 32 + quad * 8];
#pragma unroll
      for (int mt = 0; mt < MT; mt++)
#pragma unroll
        for (int nt = 0; nt < NT; nt++)
          acc[mt][nt] = __builtin_amdgcn_mfma_f32_16x16x32_bf16(af[mt], bfr[nt], acc[mt][nt], 0, 0, 0);
    }
    buf ^= 1;
  }

#pragma unroll
  for (int mt = 0; mt < MT; mt++) {
#pragma unroll
    for (int nt = 0; nt < NT; nt++) {
      int row0 = bm * TM + wm * MT * 16 + mt * 16 + quad * 4;
      int col = bn * TN + wn * NT * 16 + nt * 16 + l16;
      if (EPI == 0) {
        int b = row0 >> 11, l = row0 & 2047;
        int which = col >> 10, d = col & 1023;
        int hh = d >> 6, hdi = d & 63;
        size_t bh = (size_t)(b * 16 + hh);
        if (which == 0) {
#pragma unroll
          for (int r = 0; r < 4; r++)
            ob0[(bh * 2048 + l + r) * 64 + hdi] = (bf16)(acc[mt][nt][r] * QSCALE);
        } else if (which == 1) {
#pragma unroll
          for (int r = 0; r < 4; r++)
            ob1[(bh * 2048 + l + r) * 64 + hdi] = (bf16)acc[mt][nt][r];
        } else {
          short4v v4;
#pragma unroll
          for (int r = 0; r < 4; r++) v4[r] = f2bf(acc[mt][nt][r]);
          *(short4v*)&ob2[(bh * 64 + hdi) * 2048 + l] = v4;
        }
      } else {
#pragma unroll
        for (int r = 0; r < 4; r++) {
          int row = row0 + r;
          float v = acc[mt][nt][r];
          size_t idx = (size_t)row * N + col;
          outf[idx] = v + bias[col] + resid[idx];
        }
      }
    }
  }
}

// ---------------- 8-phase 256x256 GEMM (mlp1: M=N=4096, K=1024) ------
// m201-template port; see R7 notes. Verified win (mlp1 off top-5).
__global__ __launch_bounds__(512, 2) void gemm8p_gelu(
    const bf16* __restrict__ A, const bf16* __restrict__ Bt,
    const float* __restrict__ bias, bf16* __restrict__ ob0)
{
  __shared__ __align__(16) bf16 As[4 * 8192];   // [buf][kk][256][32] 64KB
  __shared__ __align__(16) bf16 Bs[4 * 8192];   // [buf][kk][256][32] 64KB
  const int tid = threadIdx.x, lane = tid & 63, wave = tid >> 6;
  const int quad = lane >> 4, l16 = lane & 15;
  const int wm = wave >> 2, wn = wave & 3;       // 2 x 4 wave grid

  int flat = blockIdx.x + gridDim.x * blockIdx.y; // grid 16x16 = 256
  int xcd = flat & 7, rr = flat >> 3;
  int bn = xcd * 2 + (rr & 1);
  int bm = rr >> 1;

  auto stA = [&](int buf, int ktile, int half) {
    const bf16* g = A + (size_t)ktile * ATILE +
                    ((size_t)bm * 256 + half * 128) * 32 + (size_t)tid * 8;
    g2l16(g, &As[(buf * 2 + (ktile & 1)) * 8192 + half * 4096 + wave * 512]);
  };
  auto stB = [&](int buf, int ktile, int half) {
    const bf16* g = Bt + (size_t)ktile * ATILE +
                    ((size_t)bn * 256 + half * 128) * 32 + (size_t)tid * 8;
    g2l16(g, &Bs[(buf * 2 + (ktile & 1)) * 8192 + half * 4096 + wave * 512]);
  };

  f32x4 acc[8][4] = {};
  bf16x8 af[4][2], bfr[4][2];

  stA(0, 0, 0); stA(0, 0, 1); stA(0, 1, 0); stA(0, 1, 1);
  stB(0, 0, 0); stB(0, 0, 1); stB(0, 1, 0); stB(0, 1, 1);
  asm volatile("s_waitcnt vmcnt(0)" ::: "memory");
  __builtin_amdgcn_s_barrier();

  for (int kt = 0; kt < 16; kt++) {
    const int buf = kt & 1, nbuf = buf ^ 1;
    const bool more = (kt + 1) < 16;
    const int kA = (kt + 1) * 2;

    // ---- phase 1
#pragma unroll
    for (int mt = 0; mt < 4; mt++)
#pragma unroll
      for (int kk = 0; kk < 2; kk++)
        af[mt][kk] = *(const bf16x8*)&As[(buf * 2 + kk) * 8192 +
                       (wm * 128 + mt * 16 + l16) * 32 + quad * 8];
#pragma unroll
    for (int nt = 0; nt < 2; nt++)
#pragma unroll
      for (int kk = 0; kk < 2; kk++)
        bfr[nt][kk] = *(const bf16x8*)&Bs[(buf * 2 + kk) * 8192 +
                        (wn * 64 + nt * 16 + l16) * 32 + quad * 8];
    if (more) { stA(nbuf, kA, 0); stA(nbuf, kA, 1); stA(nbuf, kA + 1, 0); stA(nbuf, kA + 1, 1); }
    __builtin_amdgcn_s_barrier();
    asm volatile("s_waitcnt lgkmcnt(0)" ::: "memory");
    __builtin_amdgcn_sched_barrier(0);
    __builtin_amdgcn_s_setprio(1);
#pragma unroll
    for (int mt = 0; mt < 4; mt++)
#pragma unroll
      for (int nt = 0; nt < 2; nt++)
#pragma unroll
        for (int kk = 0; kk < 2; kk++)
          acc[mt][nt] = __builtin_amdgcn_mfma_f32_16x16x32_bf16(af[mt][kk], bfr[nt][kk], acc[mt][nt], 0, 0, 0);
    __builtin_amdgcn_s_setprio(0);
    __builtin_amdgcn_s_barrier();

    // ---- phase 2
#pragma unroll
    for (int nt = 2; nt < 4; nt++)
#pragma unroll
      for (int kk = 0; kk < 2; kk++)
        bfr[nt][kk] = *(const bf16x8*)&Bs[(buf * 2 + kk) * 8192 +
                        (wn * 64 + nt * 16 + l16) * 32 + quad * 8];
    if (more) { stB(nbuf, kA, 0); stB(nbuf, kA, 1); stB(nbuf, kA + 1, 0); stB(nbuf, kA + 1, 1); }
    __builtin_amdgcn_s_barrier();
    asm volatile("s_waitcnt lgkmcnt(0)" ::: "memory");
    __builtin_amdgcn_sched_barrier(0);
    __builtin_amdgcn_s_setprio(1);
#pragma unroll
    for (int mt = 0; mt < 4; mt++)
#pragma unroll
      for (int nt = 2; nt < 4; nt++)
#pragma unroll
        for (int kk = 0; kk < 2; kk++)
          acc[mt][nt] = __builtin_amdgcn_mfma_f32_16x16x32_bf16(af[mt][kk], bfr[nt][kk], acc[mt][nt], 0, 0, 0);
    __builtin_amdgcn_s_setprio(0);
    __builtin_amdgcn_s_barrier();

    // ---- phase 3
#pragma unroll
    for (int mt = 0; mt < 4; mt++)
#pragma unroll
      for (int kk = 0; kk < 2; kk++)
        af[mt][kk] = *(const bf16x8*)&As[(buf * 2 + kk) * 8192 +
                       (wm * 128 + (mt + 4) * 16 + l16) * 32 + quad * 8];
    __builtin_amdgcn_s_barrier();
    asm volatile("s_waitcnt lgkmcnt(0)" ::: "memory");
    __builtin_amdgcn_sched_barrier(0);
    __builtin_amdgcn_s_setprio(1);
#pragma unroll
    for (int mt = 0; mt < 4; mt++)
#pragma unroll
      for (int nt = 0; nt < 2; nt++)
#pragma unroll
        for (int kk = 0; kk < 2; kk++)
          acc[mt + 4][nt] = __builtin_amdgcn_mfma_f32_16x16x32_bf16(af[mt][kk], bfr[nt][kk], acc[mt + 4][nt], 0, 0, 0);
    __builtin_amdgcn_s_setprio(0);
    __builtin_amdgcn_s_barrier();

    // ---- phase 4
    __builtin_amdgcn_s_setprio(1);
#pragma unroll
    for (int mt = 0; mt < 4; mt++)
#pragma unroll
      for (int nt = 2; nt < 4; nt++)
#pragma unroll
        for (int kk = 0; kk < 2; kk++)
          acc[mt + 4][nt] = __builtin_amdgcn_mfma_f32_16x16x32_bf16(af[mt][kk], bfr[nt][kk], acc[mt + 4][nt], 0, 0, 0);
    __builtin_amdgcn_s_setprio(0);
    asm volatile("s_waitcnt vmcnt(0)" ::: "memory");
    __builtin_amdgcn_s_barrier();
  }

#pragma unroll
  for (int mt = 0; mt < 8; mt++) {
#pragma unroll
    for (int nt = 0; nt < 4; nt++) {
      int row0 = bm * 256 + wm * 128 + mt * 16 + quad * 4;
      int col = bn * 256 + wn * 64 + nt * 16 + l16;
      float bcol = bias[col];
#pragma unroll
      for (int r = 0; r < 4; r++) {
        int row = row0 + r;
        float t = acc[mt][nt][r] + bcol;
        float a = 0.7978845608028654f * t * (1.f + 0.044715f * t * t);
        float g = 0.5f * t * (1.f + fast_tanh(a));
        ob0[(size_t)(col >> 5) * ATILE + (size_t)row * 32 + (col & 31)] = (bf16)g;
      }
    }
  }
}

// ---------------- flash attention v16 ----------------
// v14 skeleton (2 barriers, reg-prefetch staging, kpos-permuted K for
// full-rate PV) + T15 2-deep P pipeline: per kt, compute
// QK(kt) -> PV(kt-1) -> SM(kt). PV(kt-1) [MFMA, uses pfPrev] is
// independent of SM(kt) [VALU, uses this kt's sacc] -> the wave issues
// SM's VALU while the matrix pipe runs PV, overlapping the phases that
// R11's counters showed alternating (MfmaUtil 26 / VALUBusy 41).
// V is double-buffered (PV reads V(kt-1) after V(kt) staged): Ks 16KB +
// Vs 2x16KB = 48KB, still 2 blocks/CU. pf ping-pong via unroll-by-2
// body (static register indexing, rule #20). Hazards: each buffer's
// reads complete >=1 barrier before its overwrite (desk-checked).
__global__ __launch_bounds__(256, 2) void flash_attn(
    const bf16* __restrict__ Q, const bf16* __restrict__ Kg,
    const bf16* __restrict__ Vg, bf16* __restrict__ O)
{
  __shared__ __align__(16) bf16 Ks[128 * 64];     // [virt kpos][hd]
  __shared__ __align__(16) bf16 Vs[2][64 * 128];  // [buf][hd][kpos]
  const int tid = threadIdx.x, lane = tid & 63, wave = tid >> 6;
  const int quad = lane >> 4, l16 = lane & 15;
  const int qt = blockIdx.x, bh = blockIdx.y;
  const int b = bh >> 4, h = bh & 15;

  const bf16* qg = Q + ((size_t)bh * 2048 + qt * 128) * 64;
  const bf16* kg = Kg + (size_t)bh * 2048 * 64;
  const bf16* vg = Vg + (size_t)bh * 64 * 2048;

  // K write: actual row a0 -> virtual row v0 (kpos permutation for
  // full-rate PV); pass i advances +32 rows = +4096B (swizzle invariant).
  const int a0 = tid >> 3;
  const int a5 = a0 & 31;
  const int vb = ((a5 >> 2) & 1) * 16 + (a5 >> 3) * 4 + (a5 & 3);
  const int v0 = (a0 & ~31) + vb;
  const int kw0 = (v0 << 7) + (((tid & 7) << 4) ^ ((v0 & 7) << 4));
  const int vw0 = ((tid >> 4) << 8) + (((tid & 15) << 4) ^ (((tid >> 4) & 7) << 4));

  bf16x8 qf[2][2];
#pragma unroll
  for (int s = 0; s < 2; s++)
#pragma unroll
    for (int kk = 0; kk < 2; kk++)
      qf[s][kk] = *(const bf16x8*)&qg[(size_t)(wave * 32 + s * 16 + l16) * 64 + kk * 32 + quad * 8];

  f32x4 oacc[2][4] = {};
  float lrow[2] = {0.f, 0.f};
  bf16x8 pf0[2][4], pf1[2][4];     // ping-pong P fragments

  bf16x8 kreg[4], vreg[4];
#pragma unroll
  for (int i = 0; i < 4; i++) {
    int t = tid + i * 256;
    kreg[i] = *(const bf16x8*)&kg[(size_t)(t >> 3) * 64 + (t & 7) * 8];
    vreg[i] = *(const bf16x8*)&vg[(size_t)(t >> 4) * 2048 + (t & 15) * 8];
  }

  // one pipeline step: stage tile kt (K->Ks, V->Vs[vbuf]); prefetch kt+1;
  // QK(kt); PV(kt-1) from Vs[vbuf^1] with pfP; SM(kt) -> pfC.
  auto step = [&](int kt, int vbuf, bf16x8 (&pfP)[2][4],
                  bf16x8 (&pfC)[2][4], bool doPV) {
    __syncthreads();                  // all waves done with prior compute
#pragma unroll
    for (int i = 0; i < 4; i++) {
      *(bf16x8*)((char*)Ks + kw0 + i * 4096) = kreg[i];
      *(bf16x8*)((char*)&Vs[vbuf][0] + vw0 + i * 4096) = vreg[i];
    }
    __syncthreads();                  // publish tile kt
    if (kt + 1 < 16) {
#pragma unroll
      for (int i = 0; i < 4; i++) {
        int t = tid + i * 256;
        kreg[i] = *(const bf16x8*)&kg[((size_t)(kt + 1) * 128 + (t >> 3)) * 64 + (t & 7) * 8];
        vreg[i] = *(const bf16x8*)&vg[(size_t)(t >> 4) * 2048 + (kt + 1) * 128 + (t & 15) * 8];
      }
    }

    // QK(kt): 8 virtual kpos-tiles x 2 q-subtiles, K-dim 64 = 2 chunks
    f32x4 sacc[2][8] = {};
#pragma unroll
    for (int kk = 0; kk < 2; kk++) {
#pragma unroll
      for (int ct = 0; ct < 8; ct++) {
        int krow = ct * 16 + l16;
        bf16x8 kf = *(const bf16x8*)((const char*)Ks + krow * 128 +
                                     ((kk * 64 + quad * 16) ^ ((l16 & 7) << 4)));
        sacc[0][ct] = __builtin_amdgcn_mfma_f32_16x16x32_bf16(kf, qf[0][kk], sacc[0][ct], 0, 0, 0);
        sacc[1][ct] = __builtin_amdgcn_mfma_f32_16x16x32_bf16(kf, qf[1][kk], sacc[1][ct], 0, 0, 0);
      }
    }

    // PV(kt-1) from the OTHER V buffer with pfP: runs on the matrix pipe
    // while SM(kt) below fills the VALU/TRANS pipes (independent).
    if (doPV) {
#pragma unroll
      for (int ot = 0; ot < 4; ot++) {
#pragma unroll
        for (int c = 0; c < 4; c++) {
          int vrow = ot * 16 + l16;
          bf16x8 vf = *(const bf16x8*)((const char*)&Vs[vbuf ^ 1][0] + vrow * 256 +
                                       ((c * 64 + quad * 16) ^ ((l16 & 7) << 4)));
          oacc[0][ot] = __builtin_amdgcn_mfma_f32_16x16x32_bf16(vf, pfP[0][c], oacc[0][ot], 0, 0, 0);
          oacc[1][ot] = __builtin_amdgcn_mfma_f32_16x16x32_bf16(vf, pfP[1][c], oacc[1][ot], 0, 0, 0);
        }
      }
    }

    // SM(kt): no-max softmax (exp2 domain); pack into K=32 B-fragments
#pragma unroll
    for (int s = 0; s < 2; s++) {
      float sum = 0.f;
#pragma unroll
      for (int c = 0; c < 4; c++) {
        uint4v u;
#pragma unroll
        for (int bb = 0; bb < 2; bb++) {
          float p0 = fast_exp2(sacc[s][2 * c + bb][0]);
          float p1 = fast_exp2(sacc[s][2 * c + bb][1]);
          float p2 = fast_exp2(sacc[s][2 * c + bb][2]);
          float p3 = fast_exp2(sacc[s][2 * c + bb][3]);
          sum += (p0 + p1) + (p2 + p3);
          u[bb * 2 + 0] = pk_bf16(p0, p1);
          u[bb * 2 + 1] = pk_bf16(p2, p3);
        }
        pfC[s][c] = __builtin_bit_cast(bf16x8, u);
      }
      lrow[s] += sum;
    }
  };

  for (int k2 = 0; k2 < 8; k2++) {
    step(2 * k2,     0, pf1, pf0, k2 > 0);   // even kt: V->buf0, PV(odd prev)
    step(2 * k2 + 1, 1, pf0, pf1, true);     // odd kt:  V->buf1, PV(even prev)
  }

  // drain: PV(15) — P in pf1, V(15) in buf 1
#pragma unroll
  for (int ot = 0; ot < 4; ot++) {
#pragma unroll
    for (int c = 0; c < 4; c++) {
      int vrow = ot * 16 + l16;
      bf16x8 vf = *(const bf16x8*)((const char*)&Vs[1][0] + vrow * 256 +
                                   ((c * 64 + quad * 16) ^ ((l16 & 7) << 4)));
      oacc[0][ot] = __builtin_amdgcn_mfma_f32_16x16x32_bf16(vf, pf1[0][c], oacc[0][ot], 0, 0, 0);
      oacc[1][ot] = __builtin_amdgcn_mfma_f32_16x16x32_bf16(vf, pf1[1][c], oacc[1][ot], 0, 0, 0);
    }
  }

  // epilogue: finish lrow reduce (quads hold disjoint kpos partials), store
#pragma unroll
  for (int s = 0; s < 2; s++) {
    float l = lrow[s];
    l += __shfl_xor(l, 16);
    l += __shfl_xor(l, 32);
    float inv = 1.f / l;
    int qrow = qt * 128 + wave * 32 + s * 16 + l16;
    size_t grow = (size_t)b * 2048 + qrow;
#pragma unroll
    for (int ot = 0; ot < 4; ot++) {
      int col = h * 64 + ot * 16 + quad * 4;
      short4v o4;
#pragma unroll
      for (int r = 0; r < 4; r++) o4[r] = f2bf(oacc[s][ot][r] * inv);
      *(short4v*)&O[(size_t)(col >> 5) * ATILE + grow * 32 + (col & 31)] = o4;
    }
  }
}

// ---------------- launch ----------------
extern "C" void kernel_launch(void* const* d_in, const int* in_sizes, int n_in,
                              void* d_out, int out_size, void* d_ws, size_t ws_size,
                              hipStream_t stream)
{
  const float* x     = (const float*)d_in[0];
  const float* ln1s  = (const float*)d_in[1];
  const float* ln1b  = (const float*)d_in[2];
  const float* wqkv  = (const float*)d_in[3];
  const float* wproj = (const float*)d_in[4];
  const float* bproj = (const float*)d_in[5];
  const float* ln2s  = (const float*)d_in[6];
  const float* ln2b  = (const float*)d_in[7];
  const float* wmlp1 = (const float*)d_in[8];
  const float* bmlp1 = (const float*)d_in[9];
  const float* wmlp2 = (const float*)d_in[10];
  const float* bmlp2 = (const float*)d_in[11];
  float* out = (float*)d_out;

  char* ws = (char*)d_ws;
  bf16* wqkv_t  = (bf16*)(ws + 0);          // tiled [32][3072][32]
  bf16* wproj_t = (bf16*)(ws + 6291456);    // tiled [32][1024][32]
  bf16* wmlp1_t = (bf16*)(ws + 8388608);    // tiled [32][4096][32]
  bf16* wmlp2_t = (bf16*)(ws + 16777216);   // tiled [128][1024][32]
  bf16* hbuf    = (bf16*)(ws + 25165824);   // tiled [32][4096][32]
  bf16* qb      = (bf16*)(ws + 33554432);   // [32,2048,64]
  bf16* kb      = (bf16*)(ws + 41943040);   // [32,2048,64]
  bf16* vb      = (bf16*)(ws + 50331648);   // [32,64,2048]
  bf16* aout    = (bf16*)(ws + 58720256);   // tiled [32][4096][32]
  bf16* mbuf    = (bf16*)(ws + 33554432);   // tiled [128][4096][32] aliases q/k/v/aout

  prep_kernel<<<16384, 256, 0, stream>>>(wqkv, wproj, wmlp1, wmlp2,
                                         wqkv_t, wproj_t, wmlp1_t, wmlp2_t,
                                         x, ln1s, ln1b, hbuf);
  // qkv: 2-phase 128x128 (measured best for this shape, R9/R10 A/B)
  gemm_tt<4, 4, 1, 0><<<dim3(24, 32), 256, 0, stream>>>(hbuf, wqkv_t, 3072, 1024,
                                                        nullptr, nullptr, nullptr, qb, kb, vb);
  flash_attn<<<dim3(16, 32), 256, 0, stream>>>(qb, kb, vb, aout);
  gemm_tt<2, 4, 2, 1><<<dim3(8, 64), 256, 0, stream>>>(aout, wproj_t, 1024, 1024,
                                                       bproj, x, out, nullptr, nullptr, nullptr);
  ln_kernel<<<4096, 256, 0, stream>>>(out, ln2s, ln2b, hbuf);
  // mlp1: 8-phase 256x256 kernel, grid 16x16 = 256 blocks = 1/CU
  gemm8p_gelu<<<dim3(16, 16), 512, 0, stream>>>(hbuf, wmlp1_t, bmlp1, mbuf);
  gemm_tt<2, 4, 2, 1><<<dim3(8, 64), 256, 0, stream>>>(mbuf, wmlp2_t, 1024, 4096,
                                                       bmlp2, out, out, nullptr, nullptr, nullptr);
}